// Round 12
// baseline (546.241 us; speedup 1.0000x reference)
//
#include <hip/hip_runtime.h>
#include <hip/hip_bf16.h>
#include <hip/hip_cooperative_groups.h>

namespace cg = cooperative_groups;

// InfoNCE loss, B=8, N=2048, D=256, T=0.1 — single cooperative kernel:
// scan -> sync -> gather -> sync -> counted-vmcnt MFMA main -> sync ->
// finalize. All batch-b data stays XCD-local (b = lin&7 in every phase).
// Fallback to the proven 4-kernel chain if cooperative launch is rejected.

#define B_ 8
#define N_ 2048
#define D_ 256
#define NCH 6     // column-tile chunks; grid = 8*32*6 = 1536 = 6 blocks/CU
#define BROWS 64  // rows per block = 4 waves x 16 rows
#define TCOLS 16  // columns per LDS tile (8 KB); 3 bufs = 24 KB
#define TILEB (TCOLS * 512)
#define GRID_ (B_ * 32 * NCH)
#define NEGB -16384.0f

typedef __attribute__((ext_vector_type(8))) short bf16x8;
typedef __attribute__((ext_vector_type(4))) float f32x4;

__device__ __forceinline__ void gload16(const void* g, void* l) {
  __builtin_amdgcn_global_load_lds(
      (const __attribute__((address_space(1))) void*)g,
      (__attribute__((address_space(3))) void*)l, 16, 0, 0);
}

// ---------------- phase bodies (shared by fused + fallback) ----------------

// Scan one batch: dtype-detect, prefix-scan mask, compacted idx/gc (+pad),
// mcnt. Caller passes block-local scratch. b==0/tid==0 zeroes accumulators.
__device__ __forceinline__ void scan_body(
    const void* __restrict__ maskRaw, const int* __restrict__ groups,
    int* __restrict__ idx, int* __restrict__ gc, int* __restrict__ mcnt,
    float* gsum, int* done, int b, int tid, int* cnt_s, int* warpOff) {
  if (tid == 0) *cnt_s = 0;
  __syncthreads();
  const int4* p4 = (const int4*)maskRaw;
  int c = 0;
  for (int i = tid; i < 1024; i += 256) {  // first 16KB: safe for both dtypes
    const int4 v = p4[i];
    c += ((v.x & 0xFFFFFF00) != 0) + ((v.y & 0xFFFFFF00) != 0) +
         ((v.z & 0xFFFFFF00) != 0) + ((v.w & 0xFFFFFF00) != 0);
  }
  atomicAdd(cnt_s, c);
  __syncthreads();
  const bool isInt = (*cnt_s == 0);

  unsigned int bits = 0;
  if (isInt) {
    const int* ip = (const int*)maskRaw + b * N_ + tid * 8;
#pragma unroll
    for (int e = 0; e < 8; e++) bits |= (unsigned)(ip[e] != 0) << e;
  } else {
    const unsigned char* bp = (const unsigned char*)maskRaw + b * N_ + tid * 8;
#pragma unroll
    for (int e = 0; e < 8; e++) bits |= (unsigned)(bp[e] != 0) << e;
  }
  const int myc = __popc(bits);
  int pre = myc;
#pragma unroll
  for (int s = 1; s < 64; s <<= 1) {
    const int t = __shfl_up(pre, s);
    if ((tid & 63) >= s) pre += t;
  }
  const int w = tid >> 6;
  if ((tid & 63) == 63) warpOff[w] = pre;
  __syncthreads();
  int wbase = 0;
#pragma unroll
  for (int ww = 0; ww < 4; ww++) wbase += (ww < w) ? warpOff[ww] : 0;
  int pos = wbase + pre - myc;
  const int m = warpOff[0] + warpOff[1] + warpOff[2] + warpOff[3];

  const int* gp = groups + b * N_;
#pragma unroll
  for (int e = 0; e < 8; e++) {
    if (bits & (1u << e)) {
      const int i = tid * 8 + e;
      idx[b * N_ + pos] = i;
      gc[b * N_ + pos] = gp[i];
      pos++;
    }
  }
  if (tid == 0) mcnt[b] = m;
  const int mpad = (m + 63) & ~63;
  if (tid < 64 && m + tid < mpad) gc[b * N_ + m + tid] = 0x10000;
  if (b == 0 && tid == 0) { gsum[0] = 0.f; gsum[1] = 0.f; *done = 0; }
}

// Gather/normalize rows g0*4+w for g0 in [rr, mpad/4) step `stride`.
__device__ __forceinline__ void gather_body(
    const float* __restrict__ emb, const int* __restrict__ idx,
    const int* __restrict__ mcnt, unsigned short* __restrict__ zc,
    int b, int rr, int stride, int w, int l) {
  const int m = mcnt[b];
  const int mpad = (m + 63) & ~63;
  for (int g0 = rr; g0 < (mpad >> 2); g0 += stride) {
    const int k = g0 * 4 + w;
    ushort4 o = {0, 0, 0, 0};
    if (k < m) {
      const int i = idx[b * N_ + k];
      const float4 v = *(const float4*)(emb + ((size_t)b * N_ + i) * D_ + l * 4);
      float ss = v.x * v.x + v.y * v.y + v.z * v.z + v.w * v.w;
#pragma unroll
      for (int s = 1; s < 64; s <<= 1) ss += __shfl_xor(ss, s);
      const float inv = 1.f / fmaxf(sqrtf(ss), 1e-12f);
      union { ushort4 u; __hip_bfloat162 h[2]; } p;
      p.h[0] = __float22bfloat162_rn(float2{v.x * inv, v.y * inv});
      p.h[1] = __float22bfloat162_rn(float2{v.z * inv, v.w * inv});
      o = p.u;
    }
    *(ushort4*)(zc + ((size_t)b * N_ + k) * D_ + l * 4) = o;
  }
}

// Counted-vmcnt triple-buffered MFMA main for one (b, x, y) block.
__device__ __forceinline__ void main_body(
    const unsigned short* __restrict__ zc, const int* __restrict__ gc,
    float* __restrict__ pd, float* __restrict__ pn,
    int b, int x, int y, int m, int tid,
    unsigned short (*colZ)[TCOLS * 256], int* gjAll) {
  const int rowBase = x * BROWS;
  const int ntiles = (m + TCOLS - 1) / TCOLS;
  const int nt = (y < ntiles) ? ((ntiles - y + NCH - 1) / NCH) : 0;
  if (rowBase >= m || nt <= 0) return;

  const int w = tid >> 6, l = tid & 63, l15 = l & 15, lg = l >> 4;
  const unsigned short* zb = zc + (size_t)b * N_ * D_;
  const int* gb = gc + b * N_;

  const int srcOff = (tid * 16) ^ (((tid >> 5) & 7) << 4);
  const int ldsOff = tid * 16;

#define STAGE(buf, ctv)                                                \
  {                                                                    \
    const char* _s = (const char*)zb + (size_t)(ctv) * TILEB + srcOff; \
    char* _l = (char*)colZ + (buf) * TILEB + ldsOff;                   \
    gload16(_s, _l);                                                   \
    gload16(_s + 4096, _l + 4096);                                     \
  }

  STAGE(0, y);
  if (nt > 1) STAGE(1, y + NCH);
  {
    const int t = tid >> 4;
    if (t < nt) gjAll[tid] = gb[(y + t * NCH) * TCOLS + (tid & 15)];
  }
  bf16x8 afrag[8];
  const int arow = rowBase + w * 16 + l15;
#pragma unroll
  for (int kt = 0; kt < 8; kt++)
    afrag[kt] = *(const bf16x8*)(zb + (size_t)arow * D_ + kt * 32 + lg * 8);

  int irow[4], gi[4];
#pragma unroll
  for (int r = 0; r < 4; r++) {
    irow[r] = rowBase + w * 16 + lg * 4 + r;
    gi[r] = gb[irow[r]];
  }

  float dP[4] = {0.f, 0.f, 0.f, 0.f};
  float nP[4] = {0.f, 0.f, 0.f, 0.f};

  __syncthreads();  // full drain once (tiles 0/1 + gjAll + afrag landed)

  for (int it = 0; it < nt; it++) {
    const int ct = y + it * NCH;
    if (it < nt - 1) {
      asm volatile("s_waitcnt vmcnt(2)" ::: "memory");
    } else {
      asm volatile("s_waitcnt vmcnt(0)" ::: "memory");
    }
    __builtin_amdgcn_s_barrier();
    if (it + 2 < nt) STAGE((it + 2) % 3, ct + 2 * NCH);
    const bool diagT = ((ct >> 2) == x);
    const char* bufc = (const char*)colZ + (it % 3) * TILEB;
    {
      f32x4 acc = {0.f, 0.f, 0.f, 0.f};
      const char* bbase = bufc + l15 * 512;
      const int bx = (l15 & 7) << 4;
#pragma unroll
      for (int kt = 0; kt < 8; kt++) {
        const bf16x8 bfrag = *(const bf16x8*)(bbase + ((lg * 16 + kt * 64) ^ bx));
        acc = __builtin_amdgcn_mfma_f32_16x16x32_bf16(afrag[kt], bfrag, acc, 0, 0, 0);
      }
      const int j = ct * TCOLS + l15;
      const int gj = gjAll[it * 16 + l15];
      const float bias = (gj & 0x10000) ? NEGB : 0.f;
#pragma unroll
      for (int r = 0; r < 4; r++) {
        float a0 = bias;
        if (diagT && j == irow[r]) a0 = NEGB;
        const float e0 = __builtin_exp2f(fmaf(acc[r], 14.4269504089f, a0));
        dP[r] += e0;
        if (gj == gi[r]) nP[r] += e0;
      }
    }
  }

#pragma unroll
  for (int r = 0; r < 4; r++) {
    float d = dP[r], n = nP[r];
#pragma unroll
    for (int mm = 1; mm < 16; mm <<= 1) {
      d += __shfl_xor(d, mm);
      n += __shfl_xor(n, mm);
    }
    if (l15 == 0) {
      const int row = rowBase + w * 16 + lg * 4 + r;
      const size_t o = ((size_t)y * B_ + b) * N_ + row;
      pd[o] = d;
      pn[o] = n;
    }
  }
#undef STAGE
}

// Finalize 256 rows (batch fb, rows kbase..kbase+255); ticket-last of nblk
// participating blocks writes the scalar.
__device__ __forceinline__ void finalize_body(
    const float* __restrict__ pd, const float* __restrict__ pn,
    const int* __restrict__ mcnt, float* gsum, int* done, float* out,
    int fb, int kbase, int nblk, int tid, float* sc, float* sn, int* isLast) {
  const int fm = mcnt[fb];
  const int k = kbase + tid;
  float contrib = 0.f, cnt = 0.f;
  if (k < fm) {
    const int nch = min(NCH, (fm + TCOLS - 1) / TCOLS);
    float d = 0.f, n = 0.f;
    for (int c = 0; c < nch; c++) {
      d += pd[((size_t)c * B_ + fb) * N_ + k];
      n += pn[((size_t)c * B_ + fb) * N_ + k];
    }
    if (n > 0.f) {
      contrib = __logf(d) - __logf(n);
      cnt = 1.f;
    }
  }
#pragma unroll
  for (int s = 1; s < 64; s <<= 1) {
    contrib += __shfl_xor(contrib, s);
    cnt += __shfl_xor(cnt, s);
  }
  const int w = tid >> 6;
  if ((tid & 63) == 0) { sc[w] = contrib; sn[w] = cnt; }
  __syncthreads();
  if (tid == 0) {
    atomicAdd(&gsum[0], sc[0] + sc[1] + sc[2] + sc[3]);
    atomicAdd(&gsum[1], sn[0] + sn[1] + sn[2] + sn[3]);
    __threadfence();
    *isLast = (atomicAdd(done, 1) == nblk - 1) ? 1 : 0;
  }
  __syncthreads();
  if (*isLast && tid == 0) {
    const float s = atomicAdd(&gsum[0], 0.f);
    const float c = atomicAdd(&gsum[1], 0.f);
    out[0] = (c > 0.f) ? s / fmaxf(c, 1.f) : 0.f;
  }
}

// ---------------- fused cooperative kernel ----------------

__global__ __launch_bounds__(256, 6) void fused_kernel(
    const float* __restrict__ emb, const int* __restrict__ groups,
    const void* __restrict__ maskRaw, int* __restrict__ idx,
    int* __restrict__ gc, int* __restrict__ mcnt,
    unsigned short* __restrict__ zc, float* __restrict__ pd,
    float* __restrict__ pn, float* gsum, int* done, float* out) {
  __shared__ unsigned short colZ[3][TCOLS * 256];  // 24 KB
  __shared__ int gjAll[256];                       // 1 KB
  __shared__ int cnt_s, warpOff[4], isLast;
  __shared__ float sc[4], sn[4];

  cg::grid_group grid = cg::this_grid();
  const int lin = blockIdx.x;
  const int tid = threadIdx.x;
  const int w = tid >> 6, l = tid & 63;

  // phase 0: scan (blocks 0..7, block lin==b lands on XCD b)
  if (lin < B_)
    scan_body(maskRaw, groups, idx, gc, mcnt, gsum, done, lin, tid, &cnt_s, warpOff);
  grid.sync();

  // phase 1: gather (XCD-local, strided)
  gather_body(emb, idx, mcnt, zc, lin & 7, lin >> 3, GRID_ / B_, w, l);
  grid.sync();

  // phase 2: main (b = lin&7, x = (lin>>3)&31, y = (lin>>3)>>5)
  {
    const int b = lin & 7, rr = lin >> 3;
    main_body(zc, gc, pd, pn, b, rr & 31, rr >> 5, mcnt[b], tid, colZ, gjAll);
  }
  grid.sync();

  // phase 3: finalize (64 blocks; block lin handles batch lin&7 -> XCD-local)
  if (lin < 64)
    finalize_body(pd, pn, mcnt, gsum, done, out, lin & 7, (lin >> 3) * 256, 64,
                  tid, sc, sn, &isLast);
}

// ---------------- fallback standalone kernels (r11 chain) ----------------

__global__ void scan_kernel(const void* __restrict__ maskRaw, const int* __restrict__ groups,
                            int* __restrict__ idx, int* __restrict__ gc,
                            int* __restrict__ mcnt, float* gsum, int* done) {
  __shared__ int cnt_s, warpOff[4];
  scan_body(maskRaw, groups, idx, gc, mcnt, gsum, done, blockIdx.x, threadIdx.x,
            &cnt_s, warpOff);
}

__global__ void gather_kernel(const float* __restrict__ emb, const int* __restrict__ idx,
                              const int* __restrict__ mcnt, unsigned short* __restrict__ zc) {
  const int lin = blockIdx.x;
  gather_body(emb, idx, mcnt, zc, lin & 7, lin >> 3, 512, threadIdx.x >> 6,
              threadIdx.x & 63);
}

__global__ __launch_bounds__(256, 6) void main_kernel(
    const unsigned short* __restrict__ zc, const int* __restrict__ gc,
    const int* __restrict__ mcnt, float* __restrict__ pd, float* __restrict__ pn) {
  __shared__ unsigned short colZ[3][TCOLS * 256];
  __shared__ int gjAll[256];
  const int lin = blockIdx.x;
  const int b = lin & 7, rr = lin >> 3;
  main_body(zc, gc, pd, pn, b, rr & 31, rr >> 5, mcnt[b], threadIdx.x, colZ, gjAll);
}

__global__ void finalize_kernel(const float* __restrict__ pd, const float* __restrict__ pn,
                                const int* __restrict__ mcnt, float* gsum, int* done,
                                float* out) {
  __shared__ int isLast;
  __shared__ float sc[4], sn[4];
  const int lin = blockIdx.x;
  finalize_body(pd, pn, mcnt, gsum, done, out, lin & 7, (lin >> 3) * 256, 64,
                threadIdx.x, sc, sn, &isLast);
}

extern "C" void kernel_launch(void* const* d_in, const int* in_sizes, int n_in,
                              void* d_out, int out_size, void* d_ws, size_t ws_size,
                              hipStream_t stream) {
  const float* emb = (const float*)d_in[0];
  const int* groups = (const int*)d_in[1];
  const void* mask = d_in[2];
  float* out = (float*)d_out;

  char* ws = (char*)d_ws;
  float* gsum = (float*)ws;
  int* done = (int*)(ws + 64);
  int* mcnt = (int*)(ws + 128);
  int* idx = (int*)(ws + 192);
  int* gc = (int*)(ws + 65728);
  unsigned short* zc = (unsigned short*)(ws + 131264);
  float* pd = (float*)(ws + 8519872);
  float* pn = (float*)(ws + 9044160);

  void* kargs[] = {&emb, &groups, &mask, &idx, &gc, &mcnt, &zc, &pd, &pn,
                   &gsum, &done, &out};
  hipError_t e = hipLaunchCooperativeKernel((const void*)fused_kernel,
                                            dim3(GRID_), dim3(256), kargs, 0, stream);
  if (e != hipSuccess) {
    // fallback: proven 4-kernel chain (r11 structure, NCH=6)
    scan_kernel<<<B_, 256, 0, stream>>>(mask, groups, idx, gc, mcnt, gsum, done);
    gather_kernel<<<B_ * 512, 256, 0, stream>>>(emb, idx, mcnt, zc);
    main_kernel<<<GRID_, 256, 0, stream>>>(zc, gc, mcnt, pd, pn);
    finalize_kernel<<<64, 256, 0, stream>>>(pd, pn, mcnt, gsum, done, out);
  }
}

// Round 13
// 52.794 us; speedup vs baseline: 10.3467x; 10.3467x over previous
//
#include <hip/hip_runtime.h>
#include <hip/hip_bf16.h>

// InfoNCE loss, B=8, N=2048, D=256, T=0.1 — TWO kernels:
//  gather2: per-wave mask prefix-scan (no scan kernel, no idx array) +
//           L2-normalize -> compacted bf16 zc, XCD-local (b = lin&7).
//  main2:   r11's counted-vmcnt triple-buffered MFMA loop + fused finalize
//           via pure-atomic ticket protocol (NO threadfence -> no L2 poison).
// ws layout (~8.6 MB):
//   [0]       float gsum[16] (0: loss sum, 1: count)
//   [64]      int   done2
//   [128]     int   mcnt[B]
//   [192]     int   gdone[256]        per-(b,x) chunk tickets
//   [2048]    int   gc[B][2048]       compacted groups (pad = 0x10000)
//   [69632]   ushort zc[B][2048][256] compacted bf16-normalized rows
//   [8458240] float pd[B][2048]       per-row denom accumulators (atomic)
//   [8523776] float pn[B][2048]       per-row numer accumulators (atomic)

#define B_ 8
#define N_ 2048
#define D_ 256
#define NCH 8     // column-tile chunks (tile t -> chunk t%NCH)
#define BROWS 64  // rows per block = 4 waves x 16 rows
#define TCOLS 16  // columns per LDS tile (8 KB); 3 bufs = 24 KB -> 6 blocks/CU
#define TILEB (TCOLS * 512)
#define NEGB -16384.0f

typedef __attribute__((ext_vector_type(8))) short bf16x8;
typedef __attribute__((ext_vector_type(4))) float f32x4;

__device__ __forceinline__ void gload16(const void* g, void* l) {
  __builtin_amdgcn_global_load_lds(
      (const __attribute__((address_space(1))) void*)g,
      (__attribute__((address_space(3))) void*)l, 16, 0, 0);
}

// Fused scan+gather. 1D grid B*512, b = lin&7 (XCD-local). Each wave owns
// original row i = (lin>>3)*4 + w: computes prefix = popcount(mask[0..i))
// in-register (lane j covers 32 elements), then normalizes emb row i into
// compacted slot zc[prefix] if masked-in. Block rr==0 writes mcnt/pads;
// block (0,0) zeroes global accumulators; every wave zeroes pd/pn[i].
__global__ void gather2_kernel(const float* __restrict__ emb,
                               const int* __restrict__ groups,
                               const void* __restrict__ maskRaw,
                               int* __restrict__ gc, int* __restrict__ mcnt,
                               unsigned short* __restrict__ zc,
                               float* __restrict__ pd, float* __restrict__ pn,
                               float* gsum, int* done2, int* __restrict__ gdone,
                               float* out) {
  const int lin = blockIdx.x;
  const int b = lin & 7;
  const int rr = lin >> 3;  // 0..511
  const int tid = threadIdx.x;
  const int w = tid >> 6, l = tid & 63;
  const int i = rr * 4 + w;  // original row this wave owns

  // dtype detect over first 16KB (in-bounds for both bool and int32)
  __shared__ int cnt_s;
  if (tid == 0) cnt_s = 0;
  __syncthreads();
  {
    const int4* p4 = (const int4*)maskRaw;
    int c = 0;
    for (int q = tid; q < 1024; q += 256) {
      const int4 v = p4[q];
      c += ((v.x & 0xFFFFFF00) != 0) + ((v.y & 0xFFFFFF00) != 0) +
           ((v.z & 0xFFFFFF00) != 0) + ((v.w & 0xFFFFFF00) != 0);
    }
    atomicAdd(&cnt_s, c);
  }
  __syncthreads();
  const bool isInt = (cnt_s == 0);  // int32 0/1 values: upper bytes all zero

  // per-wave prefix: below = popcount mask[0..i), total = popcount mask[0..N)
  int below = 0, total = 0;
  if (isInt) {
    const int* mi = (const int*)maskRaw + b * N_;
    const int4* p = (const int4*)mi + l * 8;  // lane covers ints [32l, 32l+32)
#pragma unroll
    for (int c = 0; c < 8; c++) {
      const int4 v = p[c];
      const int bs = l * 32 + c * 4;
      const int n0 = (v.x != 0), n1 = (v.y != 0), n2 = (v.z != 0), n3 = (v.w != 0);
      total += n0 + n1 + n2 + n3;
      below += (bs + 0 < i ? n0 : 0) + (bs + 1 < i ? n1 : 0) +
               (bs + 2 < i ? n2 : 0) + (bs + 3 < i ? n3 : 0);
    }
  } else {
    const unsigned char* mb = (const unsigned char*)maskRaw + b * N_;
    const int4* p = (const int4*)mb + l * 2;  // lane covers bytes [32l, 32l+32)
#pragma unroll
    for (int c = 0; c < 2; c++) {
      const int4 v = p[c];
      const int dw[4] = {v.x, v.y, v.z, v.w};
#pragma unroll
      for (int q = 0; q < 4; q++) {
        int x = dw[q];
        x |= x >> 4; x |= x >> 2; x |= x >> 1;
        const int nz01 = x & 0x01010101;  // LSB of each byte = byte != 0
        total += __popc(nz01);
        const int bs = l * 32 + c * 16 + q * 4;
        const int rem = i - bs;
        const int mm = (rem >= 4) ? nz01
                     : ((rem <= 0) ? 0 : (nz01 & ((1 << (8 * rem)) - 1)));
        below += __popc(mm);
      }
    }
  }
#pragma unroll
  for (int s = 1; s < 64; s <<= 1) {
    below += __shfl_xor(below, s);
    total += __shfl_xor(total, s);
  }
  const int m = total;

  // zero per-row accumulators (each (b,i) covered exactly once)
  if (l == 0) { pd[b * N_ + i] = 0.f; pn[b * N_ + i] = 0.f; }

  // gather + normalize masked-in row into compacted slot
  const bool mk = isInt ? (((const int*)maskRaw)[b * N_ + i] != 0)
                        : (((const unsigned char*)maskRaw)[b * N_ + i] != 0);
  if (mk) {
    const int pos = below;
    const float4 v = *(const float4*)(emb + ((size_t)b * N_ + i) * D_ + l * 4);
    float ss = v.x * v.x + v.y * v.y + v.z * v.z + v.w * v.w;
#pragma unroll
    for (int s = 1; s < 64; s <<= 1) ss += __shfl_xor(ss, s);
    const float inv = 1.f / fmaxf(sqrtf(ss), 1e-12f);
    union { ushort4 u; __hip_bfloat162 h[2]; } pck;
    pck.h[0] = __float22bfloat162_rn(float2{v.x * inv, v.y * inv});
    pck.h[1] = __float22bfloat162_rn(float2{v.z * inv, v.w * inv});
    *(ushort4*)(zc + ((size_t)b * N_ + pos) * D_ + l * 4) = pck.u;
    if (l == 0) gc[b * N_ + pos] = groups[b * N_ + i];
  }

  // per-batch housekeeping (block rr==0): mcnt, pad rows, global init
  if (rr == 0) {
    if (tid == 0) mcnt[b] = m;
    const int mpad = (m + 63) & ~63;
    for (int s = m + w; s < mpad; s += 4) {  // zero pad rows + sentinel groups
      *(ushort4*)(zc + ((size_t)b * N_ + s) * D_ + l * 4) = ushort4{0, 0, 0, 0};
      if (l == 0) gc[b * N_ + s] = 0x10000;
    }
    if (b == 0) {
      gdone[tid] = 0;
      if (tid == 0) { gsum[0] = 0.f; gsum[1] = 0.f; *done2 = 0; out[0] = 0.f; }
    }
  }
}

// 1D grid B*32*NCH, b = lin&7 (XCD-local). r11's counted-vmcnt 3-buffer MFMA
// loop (unchanged), then fused finalize: per-row atomicAdd accumulators ->
// vmcnt(0) -> per-(b,x) ticket -> last chunk-block reduces its 64 rows via
// coherent atomic reads -> globally-last group writes the scalar. No fences.
__global__ __launch_bounds__(256, 6) void main2_kernel(
    const unsigned short* __restrict__ zc, const int* __restrict__ gc,
    const int* __restrict__ mcnt, float* __restrict__ pd, float* __restrict__ pn,
    float* gsum, int* done2, int* __restrict__ gdone, float* out) {
  __shared__ unsigned short colZ[3][TCOLS * 256];  // 24 KB
  __shared__ int gjAll[256];
  __shared__ int ticket_s;

  const int lin = blockIdx.x;
  const int b = lin & 7;
  const int rr = lin >> 3;     // 0..255
  const int x = rr & 31;       // row-block
  const int y = rr >> 5;       // chunk 0..7
  const int m = mcnt[b];
  const int rowBase = x * BROWS;
  if (rowBase >= m) return;
  const int ntiles = (m + TCOLS - 1) / TCOLS;
  const int nt = (y < ntiles) ? ((ntiles - y + NCH - 1) / NCH) : 0;
  if (nt <= 0) return;
  const int nact = min(NCH, ntiles);  // chunk-blocks active for this (b,x)

  const int tid = threadIdx.x;
  const int w = tid >> 6, l = tid & 63, l15 = l & 15, lg = l >> 4;
  const unsigned short* zb = zc + (size_t)b * N_ * D_;
  const int* gb = gc + b * N_;

  // per-lane pre-swizzled source offset (involution: LDS[L] = G[L ^ ((row&7)<<4)])
  const int srcOff = (tid * 16) ^ (((tid >> 5) & 7) << 4);
  const int ldsOff = tid * 16;

#define STAGE(buf, ctv)                                                \
  {                                                                    \
    const char* _s = (const char*)zb + (size_t)(ctv) * TILEB + srcOff; \
    char* _l = (char*)colZ + (buf) * TILEB + ldsOff;                   \
    gload16(_s, _l);                                                   \
    gload16(_s + 4096, _l + 4096);                                     \
  }

  STAGE(0, y);
  if (nt > 1) STAGE(1, y + NCH);
  {
    const int t = tid >> 4;
    if (t < nt) gjAll[tid] = gb[(y + t * NCH) * TCOLS + (tid & 15)];
  }
  bf16x8 afrag[8];
  const int arow = rowBase + w * 16 + l15;
#pragma unroll
  for (int kt = 0; kt < 8; kt++)
    afrag[kt] = *(const bf16x8*)(zb + (size_t)arow * D_ + kt * 32 + lg * 8);

  int irow[4], gi[4];
#pragma unroll
  for (int r = 0; r < 4; r++) {
    irow[r] = rowBase + w * 16 + lg * 4 + r;  // C/D row map
    gi[r] = gb[irow[r]];
  }

  float dP[4] = {0.f, 0.f, 0.f, 0.f};
  float nP[4] = {0.f, 0.f, 0.f, 0.f};

  __syncthreads();  // full drain once (tiles 0/1 + gjAll + afrag landed)

  for (int it = 0; it < nt; it++) {
    const int ct = y + it * NCH;
    if (it < nt - 1) {
      asm volatile("s_waitcnt vmcnt(2)" ::: "memory");
    } else {
      asm volatile("s_waitcnt vmcnt(0)" ::: "memory");
    }
    __builtin_amdgcn_s_barrier();
    if (it + 2 < nt) STAGE((it + 2) % 3, ct + 2 * NCH);
    const bool diagT = ((ct >> 2) == x);
    const char* bufc = (const char*)colZ + (it % 3) * TILEB;
    {
      f32x4 acc = {0.f, 0.f, 0.f, 0.f};
      const char* bbase = bufc + l15 * 512;
      const int bx = (l15 & 7) << 4;
#pragma unroll
      for (int kt = 0; kt < 8; kt++) {
        const bf16x8 bfrag = *(const bf16x8*)(bbase + ((lg * 16 + kt * 64) ^ bx));
        acc = __builtin_amdgcn_mfma_f32_16x16x32_bf16(afrag[kt], bfrag, acc, 0, 0, 0);
      }
      const int j = ct * TCOLS + l15;
      const int gj = gjAll[it * 16 + l15];
      const float bias = (gj & 0x10000) ? NEGB : 0.f;  // pad col -> exp == 0
#pragma unroll
      for (int r = 0; r < 4; r++) {
        float a0 = bias;
        if (diagT && j == irow[r]) a0 = NEGB;  // exclude diagonal
        const float e0 = __builtin_exp2f(fmaf(acc[r], 14.4269504089f, a0));
        dP[r] += e0;
        if (gj == gi[r]) nP[r] += e0;
      }
    }
  }

  // per-row partials -> device-scope atomic accumulators
#pragma unroll
  for (int r = 0; r < 4; r++) {
    float d = dP[r], n = nP[r];
#pragma unroll
    for (int mm = 1; mm < 16; mm <<= 1) {
      d += __shfl_xor(d, mm);
      n += __shfl_xor(n, mm);
    }
    if (l15 == 0) {
      const int row = rowBase + w * 16 + lg * 4 + r;
      atomicAdd(&pd[b * N_ + row], d);
      atomicAdd(&pn[b * N_ + row], n);
    }
  }

  // ticket: my atomics are complete (vmcnt drained) before I announce
  asm volatile("s_waitcnt vmcnt(0)" ::: "memory");
  __syncthreads();
  if (tid == 0) ticket_s = atomicAdd(&gdone[b * 32 + x], 1);
  __syncthreads();
  if (ticket_s != nact - 1) return;

  // last chunk-block of (b,x): finalize 64 rows via coherent atomic reads
  if (tid < 64) {
    float contrib = 0.f, cnt = 0.f;
    const int row = rowBase + tid;
    if (row < m) {
      const float d = atomicAdd(&pd[b * N_ + row], 0.f);  // coherent RMW read
      const float n = atomicAdd(&pn[b * N_ + row], 0.f);
      if (n > 0.f) {
        contrib = __logf(d) - __logf(n);  // -log(numer/denom)
        cnt = 1.f;
      }
    }
#pragma unroll
    for (int s = 1; s < 64; s <<= 1) {
      contrib += __shfl_xor(contrib, s);
      cnt += __shfl_xor(cnt, s);
    }
    if (tid == 0) {
      atomicAdd(&gsum[0], contrib);
      atomicAdd(&gsum[1], cnt);
      asm volatile("s_waitcnt vmcnt(0)" ::: "memory");  // gsum visible first
      int G = 0;
#pragma unroll
      for (int bb = 0; bb < B_; bb++) G += (mcnt[bb] + 63) >> 6;
      if (atomicAdd(done2, 1) == G - 1) {  // globally last group
        const float s2 = atomicAdd(&gsum[0], 0.f);
        const float c2 = atomicAdd(&gsum[1], 0.f);
        out[0] = (c2 > 0.f) ? s2 / fmaxf(c2, 1.f) : 0.f;
      }
    }
  }
#undef STAGE
}

extern "C" void kernel_launch(void* const* d_in, const int* in_sizes, int n_in,
                              void* d_out, int out_size, void* d_ws, size_t ws_size,
                              hipStream_t stream) {
  const float* emb = (const float*)d_in[0];
  const int* groups = (const int*)d_in[1];
  const void* mask = d_in[2];
  float* out = (float*)d_out;

  char* ws = (char*)d_ws;
  float* gsum = (float*)ws;
  int* done2 = (int*)(ws + 64);
  int* mcnt = (int*)(ws + 128);
  int* gdone = (int*)(ws + 192);
  int* gc = (int*)(ws + 2048);
  unsigned short* zc = (unsigned short*)(ws + 69632);
  float* pd = (float*)(ws + 8458240);
  float* pn = (float*)(ws + 8523776);

  gather2_kernel<<<B_ * 512, 256, 0, stream>>>(emb, groups, mask, gc, mcnt, zc,
                                               pd, pn, gsum, done2, gdone, out);
  main2_kernel<<<B_ * 32 * NCH, 256, 0, stream>>>(zc, gc, mcnt, pd, pn, gsum,
                                                  done2, gdone, out);
}

// Round 14
// 36.243 us; speedup vs baseline: 15.0716x; 1.4567x over previous
//
#include <hip/hip_runtime.h>
#include <hip/hip_bf16.h>

// InfoNCE loss, B=8, N=2048, D=256, T=0.1 — mask-compacted, XCD-local,
// counted-vmcnt triple-buffered main (r11 chain) with FIXED block->CU decode:
// y = rr&7, x = rr>>3 so the ~50% ACTIVE row-blocks (x*64 < m) spread over
// ALL 32 CUs per XCD (old decode x=rr&31 piled them on CUs 0..15 only).
// ws layout (~9.6 MB): same as r8/r11.

#define B_ 8
#define N_ 2048
#define D_ 256
#define NCH 8     // column-tile chunks (tile t -> chunk t%NCH)
#define BROWS 64  // rows per block = 4 waves x 16 rows
#define TCOLS 16  // columns per LDS tile (8 KB); 3 bufs = 24 KB -> 6 blocks/CU
#define TILEB (TCOLS * 512)
#define NEGB -16384.0f

typedef __attribute__((ext_vector_type(8))) short bf16x8;
typedef __attribute__((ext_vector_type(4))) float f32x4;

__device__ __forceinline__ void gload16(const void* g, void* l) {
  __builtin_amdgcn_global_load_lds(
      (const __attribute__((address_space(1))) void*)g,
      (__attribute__((address_space(3))) void*)l, 16, 0, 0);
}

// One block per batch: detect mask dtype, prefix-scan mask, emit compacted
// index list + compacted groups (+sentinel pad), per-batch count. Block 0
// also zeroes the global accumulators.
__global__ void scan_kernel(const void* __restrict__ maskRaw, const int* __restrict__ groups,
                            int* __restrict__ idx, int* __restrict__ gc,
                            int* __restrict__ mcnt, float* gsum, int* done) {
  const int b = blockIdx.x, tid = threadIdx.x;
  __shared__ int cnt_s;
  __shared__ int warpOff[4];
  if (tid == 0) cnt_s = 0;
  __syncthreads();
  // dtype detect over first 16KB (in-bounds for both bool and int32)
  const int4* p4 = (const int4*)maskRaw;
  int c = 0;
  for (int i = tid; i < 1024; i += 256) {
    const int4 v = p4[i];
    c += ((v.x & 0xFFFFFF00) != 0) + ((v.y & 0xFFFFFF00) != 0) +
         ((v.z & 0xFFFFFF00) != 0) + ((v.w & 0xFFFFFF00) != 0);
  }
  atomicAdd(&cnt_s, c);
  __syncthreads();
  const bool isInt = (cnt_s == 0);  // int32 0/1 values: upper bytes all zero

  unsigned int bits = 0;
  if (isInt) {
    const int* ip = (const int*)maskRaw + b * N_ + tid * 8;
#pragma unroll
    for (int e = 0; e < 8; e++) bits |= (unsigned)(ip[e] != 0) << e;
  } else {
    const unsigned char* bp = (const unsigned char*)maskRaw + b * N_ + tid * 8;
#pragma unroll
    for (int e = 0; e < 8; e++) bits |= (unsigned)(bp[e] != 0) << e;
  }
  const int myc = __popc(bits);
  int pre = myc;
#pragma unroll
  for (int s = 1; s < 64; s <<= 1) {
    const int t = __shfl_up(pre, s);
    if ((tid & 63) >= s) pre += t;
  }
  const int w = tid >> 6;
  if ((tid & 63) == 63) warpOff[w] = pre;
  __syncthreads();
  int wbase = 0;
#pragma unroll
  for (int ww = 0; ww < 4; ww++) wbase += (ww < w) ? warpOff[ww] : 0;
  int pos = wbase + pre - myc;  // exclusive prefix
  const int m = warpOff[0] + warpOff[1] + warpOff[2] + warpOff[3];

  const int* gp = groups + b * N_;
#pragma unroll
  for (int e = 0; e < 8; e++) {
    if (bits & (1u << e)) {
      const int i = tid * 8 + e;
      idx[b * N_ + pos] = i;
      gc[b * N_ + pos] = gp[i];
      pos++;
    }
  }
  if (tid == 0) mcnt[b] = m;
  const int mpad = (m + 63) & ~63;
  if (tid < 64 && m + tid < mpad) gc[b * N_ + m + tid] = 0x10000;  // pad sentinel
  if (b == 0 && tid == 0) { gsum[0] = 0.f; gsum[1] = 0.f; *done = 0; }
}

// One wave per compacted row: gather emb[idx[k]], L2-normalize, bf16 -> zc.
// XCD-swizzled so zc[b] is written (and cached) on XCD b.
__global__ void gather_kernel(const float* __restrict__ emb, const int* __restrict__ idx,
                              const int* __restrict__ mcnt, unsigned short* __restrict__ zc) {
  const unsigned lin = blockIdx.x;
  const int b = lin & 7;
  const int rr = lin >> 3;  // 0..511
  const int w = threadIdx.x >> 6, l = threadIdx.x & 63;
  const int k = rr * 4 + w;
  const int m = mcnt[b];
  const int mpad = (m + 63) & ~63;
  if (k >= mpad) return;
  ushort4 o = {0, 0, 0, 0};
  if (k < m) {
    const int i = idx[b * N_ + k];
    const float4 v = *(const float4*)(emb + ((size_t)b * N_ + i) * D_ + l * 4);
    float ss = v.x * v.x + v.y * v.y + v.z * v.z + v.w * v.w;
#pragma unroll
    for (int s = 1; s < 64; s <<= 1) ss += __shfl_xor(ss, s);
    const float inv = 1.f / fmaxf(sqrtf(ss), 1e-12f);
    union { ushort4 u; __hip_bfloat162 h[2]; } p;
    p.h[0] = __float22bfloat162_rn(float2{v.x * inv, v.y * inv});
    p.h[1] = __float22bfloat162_rn(float2{v.z * inv, v.w * inv});
    o = p.u;
  }
  *(ushort4*)(zc + ((size_t)b * N_ + k) * D_ + l * 4) = o;
}

// 1D grid, b = lin&7 (XCD-local), y = rr&7, x = rr>>3 (CU-spread decode).
// 4 waves x 16 rows = 64 compacted rows per block; 16-col tiles ct = y,
// y+NCH, ... in a 3-buffer rotation, 2 tiles of loads in flight; per-tile
// sync = s_waitcnt vmcnt(2) + raw s_barrier (counted-vmcnt T4 pattern).
// gj values pre-staged to LDS so the loop has NO other VM ops.
__global__ __launch_bounds__(256, 6) void main_kernel(
    const unsigned short* __restrict__ zc, const int* __restrict__ gc,
    const int* __restrict__ mcnt, float* __restrict__ pd, float* __restrict__ pn) {
  __shared__ unsigned short colZ[3][TCOLS * 256];  // 3 x 8 KB
  __shared__ int gjAll[256];                       // gj per (tile it, col)

  const unsigned lin = blockIdx.x;
  const int b = lin & 7;
  const int rr = lin >> 3;     // 0..255
  const int y = rr & 7;        // chunk 0..7   (CU-spread: active x -> all CUs)
  const int x = rr >> 3;       // row-block 0..31
  const int m = mcnt[b];
  const int rowBase = x * BROWS;
  if (rowBase >= m) return;
  const int ntiles = (m + TCOLS - 1) / TCOLS;  // 16-col tiles
  const int nt = (y < ntiles) ? ((ntiles - y + NCH - 1) / NCH) : 0;
  if (nt <= 0) return;

  const int tid = threadIdx.x;
  const int w = tid >> 6, l = tid & 63, l15 = l & 15, lg = l >> 4;
  const unsigned short* zb = zc + (size_t)b * N_ * D_;
  const int* gb = gc + b * N_;

  // per-lane pre-swizzled source offset (involution: LDS[L] = G[L ^ ((row&7)<<4)])
  const int srcOff = (tid * 16) ^ (((tid >> 5) & 7) << 4);
  const int ldsOff = tid * 16;

#define STAGE(buf, ctv)                                                        \
  {                                                                            \
    const char* _s = (const char*)zb + (size_t)(ctv) * TILEB + srcOff;         \
    char* _l = (char*)colZ + (buf) * TILEB + ldsOff;                           \
    gload16(_s, _l);                                                           \
    gload16(_s + 4096, _l + 4096);                                             \
  }

  // ---- prologue (fully drained by __syncthreads at the end) ----
  STAGE(0, y);
  if (nt > 1) STAGE(1, y + NCH);
  {  // pre-stage gj for up to 16 tiles of this chunk
    const int t = tid >> 4;
    if (t < nt) gjAll[tid] = gb[(y + t * NCH) * TCOLS + (tid & 15)];
  }
  // A fragment: lane holds row (l&15), k = kt*32 + lg*8 + e
  bf16x8 afrag[8];
  const int arow = rowBase + w * 16 + l15;
#pragma unroll
  for (int kt = 0; kt < 8; kt++)
    afrag[kt] = *(const bf16x8*)(zb + (size_t)arow * D_ + kt * 32 + lg * 8);

  int irow[4], gi[4];
#pragma unroll
  for (int r = 0; r < 4; r++) {
    irow[r] = rowBase + w * 16 + lg * 4 + r;  // C/D row map
    gi[r] = gb[irow[r]];
  }

  float dP[4] = {0.f, 0.f, 0.f, 0.f};
  float nP[4] = {0.f, 0.f, 0.f, 0.f};

  __syncthreads();  // full drain once: tiles 0(,1) + gjAll + afrag all landed

  // ---- main loop: counted vmcnt, loads 2 tiles ahead ----
  for (int it = 0; it < nt; it++) {
    const int ct = y + it * NCH;
    if (it < nt - 1) {
      asm volatile("s_waitcnt vmcnt(2)" ::: "memory");  // tile it landed
    } else {
      asm volatile("s_waitcnt vmcnt(0)" ::: "memory");
    }
    __builtin_amdgcn_s_barrier();  // all waves' tile-it loads complete
    if (it + 2 < nt) STAGE((it + 2) % 3, ct + 2 * NCH);
    const bool diagT = ((ct >> 2) == x);  // 16-col tile inside 64-row block?
    const char* bufc = (const char*)colZ + (it % 3) * TILEB;
    {
      f32x4 acc = {0.f, 0.f, 0.f, 0.f};
      const char* bbase = bufc + l15 * 512;
      const int bx = (l15 & 7) << 4;
#pragma unroll
      for (int kt = 0; kt < 8; kt++) {
        const bf16x8 bfrag = *(const bf16x8*)(bbase + ((lg * 16 + kt * 64) ^ bx));
        acc = __builtin_amdgcn_mfma_f32_16x16x32_bf16(afrag[kt], bfrag, acc, 0, 0, 0);
      }
      const int j = ct * TCOLS + l15;
      const int gj = gjAll[it * 16 + l15];             // LDS (lgkm), no VM op
      const float bias = (gj & 0x10000) ? NEGB : 0.f;  // pad col -> exp == 0
#pragma unroll
      for (int r = 0; r < 4; r++) {
        float a0 = bias;
        if (diagT && j == irow[r]) a0 = NEGB;  // exclude diagonal
        const float e0 = __builtin_exp2f(fmaf(acc[r], 14.4269504089f, a0));
        dP[r] += e0;
        if (gj == gi[r]) nP[r] += e0;
      }
    }
  }

  // reduce over the 16-lane column axis; lane l15==0 owns the row
#pragma unroll
  for (int r = 0; r < 4; r++) {
    float d = dP[r], n = nP[r];
#pragma unroll
    for (int mm = 1; mm < 16; mm <<= 1) {
      d += __shfl_xor(d, mm);
      n += __shfl_xor(n, mm);
    }
    if (l15 == 0) {
      const int row = rowBase + w * 16 + lg * 4 + r;
      const size_t o = ((size_t)y * B_ + b) * N_ + row;  // [chunk][b][row]
      pd[o] = d;
      pn[o] = n;
    }
  }
#undef STAGE
}

// Per compacted row: loss contribution; fused final division via done-counter.
__global__ void finalize_kernel(const float* __restrict__ pd, const float* __restrict__ pn,
                                const int* __restrict__ mcnt, float* gsum, int* done,
                                float* out) {
  const int g = blockIdx.x * 256 + threadIdx.x;
  const int b = g >> 11, k = g & (N_ - 1);
  const int m = mcnt[b];
  float contrib = 0.f, cnt = 0.f;
  if (k < m) {
    const int nch = min(NCH, (m + TCOLS - 1) / TCOLS);
    float d = 0.f, n = 0.f;
    for (int c = 0; c < nch; c++) {
      d += pd[((size_t)c * B_ + b) * N_ + k];
      n += pn[((size_t)c * B_ + b) * N_ + k];
    }
    if (n > 0.f) {
      contrib = __logf(d) - __logf(n);  // -log(numer/denom)
      cnt = 1.f;
    }
  }
#pragma unroll
  for (int s = 1; s < 64; s <<= 1) {
    contrib += __shfl_xor(contrib, s);
    cnt += __shfl_xor(cnt, s);
  }
  __shared__ float sc[4], sn[4];
  __shared__ bool isLast;
  const int w = threadIdx.x >> 6;
  if ((threadIdx.x & 63) == 0) { sc[w] = contrib; sn[w] = cnt; }
  __syncthreads();
  if (threadIdx.x == 0) {
    atomicAdd(&gsum[0], sc[0] + sc[1] + sc[2] + sc[3]);
    atomicAdd(&gsum[1], sn[0] + sn[1] + sn[2] + sn[3]);
    __threadfence();
    isLast = (atomicAdd(done, 1) == (int)gridDim.x - 1);
  }
  __syncthreads();
  if (isLast && threadIdx.x == 0) {
    const float s = atomicAdd(&gsum[0], 0.f);  // coherent read
    const float c = atomicAdd(&gsum[1], 0.f);
    out[0] = (c > 0.f) ? s / fmaxf(c, 1.f) : 0.f;
  }
}

extern "C" void kernel_launch(void* const* d_in, const int* in_sizes, int n_in,
                              void* d_out, int out_size, void* d_ws, size_t ws_size,
                              hipStream_t stream) {
  const float* emb = (const float*)d_in[0];
  const int* groups = (const int*)d_in[1];
  const void* mask = d_in[2];
  float* out = (float*)d_out;

  char* ws = (char*)d_ws;
  float* gsum = (float*)ws;
  int* done = (int*)(ws + 64);
  int* mcnt = (int*)(ws + 128);
  int* idx = (int*)(ws + 192);
  int* gc = (int*)(ws + 65728);
  unsigned short* zc = (unsigned short*)(ws + 131264);
  float* pd = (float*)(ws + 8519872);
  float* pn = (float*)(ws + 9044160);

  scan_kernel<<<B_, 256, 0, stream>>>(mask, groups, idx, gc, mcnt, gsum, done);
  gather_kernel<<<B_ * 512, 256, 0, stream>>>(emb, idx, mcnt, zc);
  main_kernel<<<B_ * 32 * NCH, 256, 0, stream>>>(zc, gc, mcnt, pd, pn);
  finalize_kernel<<<(B_ * N_) / 256, 256, 0, stream>>>(pd, pn, mcnt, gsum, done, out);
}